// Round 2
// baseline (585.202 us; speedup 1.0000x reference)
//
#include <hip/hip_runtime.h>

#define HASH_SIZE 16384
#define N_LEVELS 12

// One thread per (point, level) pair.
//   thread t -> b = t / 12, l = t % 12
//   writes float2 at out + t*2  (perfectly coalesced, 8 B/lane)
__global__ __launch_bounds__(256) void HashGrid1D_kernel(
    const float* __restrict__ x,
    const float* __restrict__ table,   // [HASH_SIZE, N_LEVELS*2]
    float* __restrict__ out,           // [BATCH, N_LEVELS*2]
    int total)                         // BATCH * N_LEVELS
{
    int idx = blockIdx.x * blockDim.x + threadIdx.x;
    if (idx >= total) return;

    int b = idx / N_LEVELS;
    int l = idx - b * N_LEVELS;

    float xv = x[b];
    float xc = fminf(fmaxf(xv, 0.0f), 1.0f);

    // resolutions are exactly 16 * 2^l for these params (int(round(16*2^k)))
    float res = (float)(16 << l);

    float pos = xc * res;
    float fi  = floorf(pos);
    int   i0  = (int)fi;
    float w   = pos - fi;

    int h0 = i0 & (HASH_SIZE - 1);
    int h1 = (i0 + 1) & (HASH_SIZE - 1);

    // table row stride = 24 floats; feature offset = l*2 (even -> 8B aligned)
    int off0 = h0 * (N_LEVELS * 2) + l * 2;   // stays in i32 (< 16384*24)
    int off1 = h1 * (N_LEVELS * 2) + l * 2;
    const float2 e0 = *reinterpret_cast<const float2*>(table + off0);
    const float2 e1 = *reinterpret_cast<const float2*>(table + off1);

    float omw = 1.0f - w;
    float2 r;
    r.x = omw * e0.x + w * e1.x;
    r.y = omw * e0.y + w * e1.y;

    *reinterpret_cast<float2*>(out + (size_t)idx * 2) = r;
}

extern "C" void kernel_launch(void* const* d_in, const int* in_sizes, int n_in,
                              void* d_out, int out_size, void* d_ws, size_t ws_size,
                              hipStream_t stream) {
    const float* x     = (const float*)d_in[0];
    const float* table = (const float*)d_in[1];
    float* out         = (float*)d_out;

    int batch = in_sizes[0];
    int total = batch * N_LEVELS;

    int block = 256;
    int grid  = (total + block - 1) / block;

    HashGrid1D_kernel<<<grid, block, 0, stream>>>(x, table, out, total);
}

// Round 5
// 506.730 us; speedup vs baseline: 1.1549x; 1.1549x over previous
//
#include <hip/hip_runtime.h>

#define HASH_SIZE 16384
#define N_LEVELS  12
#define LP        6   // level pairs per point

// ---------------------------------------------------------------------------
// Kernel A: build a paired, level-major gather table in workspace.
//   ws4[l*HASH_SIZE + h] = { table[h][2l], table[h][2l+1],
//                            table[(h+1)&mask][2l], table[(h+1)&mask][2l+1] }
// One 16B-aligned float4 gather in the main kernel then fetches BOTH interp
// endpoints for a level, with the hash wrap pre-resolved. 3 MB: L2-resident.
// ---------------------------------------------------------------------------
__global__ __launch_bounds__(256) void build_ws_kernel(
    const float* __restrict__ table,   // [HASH_SIZE, N_LEVELS*2]
    float4* __restrict__ ws4)          // [N_LEVELS * HASH_SIZE]
{
    int tid = blockIdx.x * blockDim.x + threadIdx.x;   // l*HASH_SIZE + h
    if (tid >= N_LEVELS * HASH_SIZE) return;
    int l  = tid >> 14;                 // / HASH_SIZE
    int h  = tid & (HASH_SIZE - 1);
    int h1 = (h + 1) & (HASH_SIZE - 1);
    const float2 e0 = *reinterpret_cast<const float2*>(table + h  * (N_LEVELS * 2) + l * 2);
    const float2 e1 = *reinterpret_cast<const float2*>(table + h1 * (N_LEVELS * 2) + l * 2);
    ws4[tid] = make_float4(e0.x, e0.y, e1.x, e1.y);
}

// ---------------------------------------------------------------------------
// Kernel B: one thread per (point, level-pair).
//   t -> b = t/6, p = t%6 -> levels {2p, 2p+1}
//   2 scattered float4 gathers (one per level), 1 coalesced float4 store.
// ---------------------------------------------------------------------------
__global__ __launch_bounds__(256) void hashgrid_main_kernel(
    const float* __restrict__ x,
    const float4* __restrict__ ws4,
    float4* __restrict__ out4,         // viewed as [BATCH*6] float4
    int total)                         // BATCH * 6
{
    int t = blockIdx.x * blockDim.x + threadIdx.x;
    if (t >= total) return;

    int b = t / LP;
    int p = t - b * LP;

    float xc = fminf(fmaxf(x[b], 0.0f), 1.0f);

    float4 r;
    #pragma unroll
    for (int k = 0; k < 2; ++k) {
        int   lvl = p * 2 + k;
        float res = (float)(16 << lvl);        // exact for these params
        float pos = xc * res;
        float fi  = floorf(pos);
        float w   = pos - fi;
        int   h0  = ((int)fi) & (HASH_SIZE - 1);

        float4 e = ws4[lvl * HASH_SIZE + h0];  // {e0.x, e0.y, e1.x, e1.y}

        float omw = 1.0f - w;
        float r0 = omw * e.x + w * e.z;
        float r1 = omw * e.y + w * e.w;
        if (k == 0) { r.x = r0; r.y = r1; }
        else        { r.z = r0; r.w = r1; }
    }

    out4[t] = r;
}

// ---------------------------------------------------------------------------
// Fallback (ws too small): round-2 direct kernel, known-correct.
// ---------------------------------------------------------------------------
__global__ __launch_bounds__(256) void hashgrid_direct_kernel(
    const float* __restrict__ x,
    const float* __restrict__ table,
    float* __restrict__ out,
    int total)                         // BATCH * N_LEVELS
{
    int idx = blockIdx.x * blockDim.x + threadIdx.x;
    if (idx >= total) return;
    int b = idx / N_LEVELS;
    int l = idx - b * N_LEVELS;
    float xc  = fminf(fmaxf(x[b], 0.0f), 1.0f);
    float res = (float)(16 << l);
    float pos = xc * res;
    float fi  = floorf(pos);
    int   i0  = (int)fi;
    float w   = pos - fi;
    int h0 = i0 & (HASH_SIZE - 1);
    int h1 = (i0 + 1) & (HASH_SIZE - 1);
    const float2 e0 = *reinterpret_cast<const float2*>(table + h0 * (N_LEVELS * 2) + l * 2);
    const float2 e1 = *reinterpret_cast<const float2*>(table + h1 * (N_LEVELS * 2) + l * 2);
    float omw = 1.0f - w;
    float2 rr;
    rr.x = omw * e0.x + w * e1.x;
    rr.y = omw * e0.y + w * e1.y;
    *reinterpret_cast<float2*>(out + (size_t)idx * 2) = rr;
}

extern "C" void kernel_launch(void* const* d_in, const int* in_sizes, int n_in,
                              void* d_out, int out_size, void* d_ws, size_t ws_size,
                              hipStream_t stream) {
    const float* x     = (const float*)d_in[0];
    const float* table = (const float*)d_in[1];
    int batch = in_sizes[0];

    const size_t ws_needed = (size_t)N_LEVELS * HASH_SIZE * sizeof(float4);  // 3 MB

    if (ws_size >= ws_needed) {
        float4* ws4 = (float4*)d_ws;

        int ta = N_LEVELS * HASH_SIZE;             // 196608
        build_ws_kernel<<<(ta + 255) / 256, 256, 0, stream>>>(table, ws4);

        int total = batch * LP;                    // BATCH * 6
        hashgrid_main_kernel<<<(total + 255) / 256, 256, 0, stream>>>(
            x, ws4, (float4*)d_out, total);
    } else {
        int total = batch * N_LEVELS;
        hashgrid_direct_kernel<<<(total + 255) / 256, 256, 0, stream>>>(
            x, table, (float*)d_out, total);
    }
}